// Round 3
// baseline (379.303 us; speedup 1.0000x reference)
//
#include <hip/hip_runtime.h>

#define START_TAG 62
#define STOP_TAG 63
#define BATCH 512
#define SLEN 1024
#define NCHAIN 64        // 32 groups x 2 directions

typedef float vf4 __attribute__((ext_vector_type(4)));
typedef short short8 __attribute__((ext_vector_type(8)));

// E' streaming layout: [g:32][dir:2][j:512][col:16][tag:64] f32 = 4KiB per step.
// dir=1 stored with j = 1023-s so BOTH directions stream strictly forward.
// Lives in ws at byte offset 1MiB.
#define E_OFF_FLOATS (1u << 18)                    // 1 MiB in floats
#define E_BYTES      134217728ull                  // 32*2*512*4096
#define WS_NEEDED    (1048576ull + E_BYTES + 65536ull)

__device__ __forceinline__ unsigned pk_bf16(float lo, float hi) {
  return __builtin_amdgcn_perm(__float_as_uint(hi), __float_as_uint(lo), 0x07060302u);
}
__device__ __forceinline__ short bf16_rne(float x) {
  unsigned u = __float_as_uint(x);
  u += 0x7FFFu + ((u >> 16) & 1u);
  return (short)(u >> 16);
}
__device__ __forceinline__ vf4 mfma16(short8 a, short8 b, vf4 c) {
  return __builtin_amdgcn_mfma_f32_16x16x32_bf16(a, b, c, 0, 0, 0);
}

// 64B load (4x dwordx4) via asm — LEGACY PATH ONLY (R0-verified binary pattern).
#define FIFO_LOAD(slot, addr)                                              \
  asm volatile("global_load_dwordx4 %0, %4, off\n\t"                       \
               "global_load_dwordx4 %1, %4, off offset:16\n\t"             \
               "global_load_dwordx4 %2, %4, off offset:32\n\t"             \
               "global_load_dwordx4 %3, %4, off offset:48"                 \
               : "=&v"(F[slot][0]), "=&v"(F[slot][1]),                     \
                 "=&v"(F[slot][2]), "=&v"(F[slot][3])                      \
               : "v"(addr) : "memory")

// depth-4 FIFO wait (legacy path): oldest 4 of 16 outstanding done.
#define FIFO_WAIT12(slot)                                                  \
  asm volatile("s_waitcnt vmcnt(12)"                                       \
               : "+v"(F[slot][0]), "+v"(F[slot][1]),                       \
                 "+v"(F[slot][2]), "+v"(F[slot][3]) :: "memory")

// ---- A fragments: E (fwd) / E^T (bwd) in bf16, custom tag<->slot map (R3/R4-verified) ----
template<int DIR>
__device__ __forceinline__ void load_A(const float* __restrict__ trans, short8 A[4][2],
                                       int q, int col) {
  const int mrow = 16 * (col >> 2) + (col & 3);
  #pragma unroll
  for (int t = 0; t < 4; ++t) {
    #pragma unroll
    for (int c = 0; c < 2; ++c) {
      short8 a;
      #pragma unroll
      for (int j = 0; j < 8; ++j) {
        int R = mrow + 4 * t, K = 16 * q + 8 * c + j;
        float tv = (DIR == 0) ? trans[R * 64 + K] : trans[K * 64 + R];
        a[j] = bf16_rne(__expf(tv));
      }
      A[t][c] = a;
    }
  }
}

template<int DIR>
__device__ __forceinline__ void epilogue(float* __restrict__ ws, const float W[16],
                                         float C, int g, int lane, int q, int col) {
  float* slab = ws + (size_t)(g * 2 + DIR) * 1024;
  #pragma unroll
  for (int t4 = 0; t4 < 4; ++t4) {
    vf4 o = {W[t4 * 4], W[t4 * 4 + 1], W[t4 * 4 + 2], W[t4 * 4 + 3]};
    *(vf4*)(slab + lane * 16 + t4 * 4) = o;
  }
  if (q == 0) ws[65536 + (g * 2 + DIR) * 16 + col] = C;
}

// One recurrence step using pre-exp'd values Fs (the loaded words ARE exp(feat)).
// Bit-identical math to the legacy fast path.
template<int DIR>
__device__ __forceinline__ void crf_step(const vf4 (&Fs)[4], const short8 (&A)[4][2],
                                         float (&W)[16]) {
  float P[16];
  #pragma unroll
  for (int t = 0; t < 4; ++t)
    #pragma unroll
    for (int i = 0; i < 4; ++i)
      P[t * 4 + i] = (DIR == 0) ? W[t * 4 + i] : W[t * 4 + i] * Fs[t][i];

  union { unsigned uu[4]; short8 s8; } B0, B1;
  B0.uu[0] = pk_bf16(P[0], P[1]);   B0.uu[1] = pk_bf16(P[2], P[3]);
  B0.uu[2] = pk_bf16(P[4], P[5]);   B0.uu[3] = pk_bf16(P[6], P[7]);
  B1.uu[0] = pk_bf16(P[8], P[9]);   B1.uu[1] = pk_bf16(P[10], P[11]);
  B1.uu[2] = pk_bf16(P[12], P[13]); B1.uu[3] = pk_bf16(P[14], P[15]);

  vf4 z4 = {0.f, 0.f, 0.f, 0.f};
  vf4 d0 = mfma16(A[0][0], B0.s8, z4);
  vf4 d1 = mfma16(A[1][0], B0.s8, z4);
  vf4 d2 = mfma16(A[2][0], B0.s8, z4);
  vf4 d3 = mfma16(A[3][0], B0.s8, z4);
  d0 = mfma16(A[0][1], B1.s8, d0);
  d1 = mfma16(A[1][1], B1.s8, d1);
  d2 = mfma16(A[2][1], B1.s8, d2);
  d3 = mfma16(A[3][1], B1.s8, d3);

  #pragma unroll
  for (int i = 0; i < 4; ++i) {
    W[i]      = (DIR == 0) ? d0[i] * Fs[0][i] : d0[i];
    W[4 + i]  = (DIR == 0) ? d1[i] * Fs[1][i] : d1[i];
    W[8 + i]  = (DIR == 0) ? d2[i] * Fs[2][i] : d2[i];
    W[12 + i] = (DIR == 0) ? d3[i] * Fs[3][i] : d3[i];
  }
}

// ---------------------------------------------------------------------------
// Streaming fast path: reads pre-exp'd, pre-transposed E' as one contiguous
// stream. 4KiB/step coalesced; E' is L2/L3-resident (just written by prepass),
// so plain compiler-managed loads with an 8-slot static prefetch array are
// enough — NO inline asm, no manual vmcnt, zero hazard surface.
// ---------------------------------------------------------------------------
template<int DIR>
__device__ __forceinline__ void chain_fast_x(const float* __restrict__ E,
                                             const float* __restrict__ trans,
                                             float* __restrict__ ws, int g) {
  const int lane = threadIdx.x & 63;
  const int q = lane >> 4, col = lane & 15;

  short8 A[4][2];
  load_A<DIR>(trans, A, q, col);

  float W[16];
  if (DIR == 0) {
    #pragma unroll
    for (int i = 0; i < 16; ++i) W[i] = 0.f;
    if (q == 3) W[14] = 1.f;                    // true tag 62 = START
  } else {
    #pragma unroll
    for (int i = 0; i < 16; ++i) W[i] = __expf(trans[STOP_TAG * 64 + 16 * q + i]);
  }

  // per-lane base into this chain's stream (float offsets); +1024 floats/step
  const float* ap = E + ((size_t)(g * 2 + DIR) * 512) * 1024
                    + (size_t)col * 64 + (size_t)q * 16;

  vf4 F[8][4];
  #pragma unroll
  for (int p = 0; p < 8; ++p)
    #pragma unroll
    for (int v = 0; v < 4; ++v)
      F[p][v] = *(const vf4*)(ap + (size_t)p * 1024 + v * 4);

  float C = 0.f, zpend = 1.f;

  // steps 0..503; each iteration prefetches step j+8 (8..511) into its slot
  for (int bk = 0; bk < 63; ++bk) {
    #pragma unroll
    for (int u = 0; u < 8; ++u) {
      crf_step<DIR>(F[u], A, W);
      const size_t jn = (size_t)(bk * 8 + u + 8);   // <= 511, always in-bounds
      #pragma unroll
      for (int v = 0; v < 4; ++v)
        F[u][v] = *(const vf4*)(ap + jn * 1024 + v * 4);
      if ((u & 3) == 3) {
        // pipelined renorm (R5-verified): apply z measured 4 steps ago
        float rz = __builtin_amdgcn_rcpf(zpend);
        C += __logf(zpend);
        #pragma unroll
        for (int i = 0; i < 16; ++i) W[i] *= rz;
        zpend = __shfl(W[0], col);              // true-tag-0 weight (> 0)
      }
    }
  }

  // steps 504..511: slots already loaded; pure compute tail
  #pragma unroll
  for (int u = 0; u < 8; ++u) {
    crf_step<DIR>(F[u], A, W);
    if ((u & 3) == 3) {
      float rz = __builtin_amdgcn_rcpf(zpend);
      C += __logf(zpend);
      #pragma unroll
      for (int i = 0; i < 16; ++i) W[i] *= rz;
      zpend = __shfl(W[0], col);
    }
  }

  epilogue<DIR>(ws, W, C, g, lane, q, col);
}

// ---------------------------------------------------------------------------
// LEGACY fast path (verbatim, R0-verified) — used when workspace can't hold E'.
// ---------------------------------------------------------------------------
template<int DIR>
__device__ __forceinline__ void chain_fast(const float* __restrict__ feats,
                                           const float* __restrict__ trans,
                                           float* __restrict__ ws, int g) {
  const int lane = threadIdx.x & 63;
  const int q = lane >> 4, col = lane & 15;
  const int b = g * 16 + col;

  short8 A[4][2];
  load_A<DIR>(trans, A, q, col);

  float W[16];
  if (DIR == 0) {
    #pragma unroll
    for (int i = 0; i < 16; ++i) W[i] = 0.f;
    if (q == 3) W[14] = 1.f;
  } else {
    #pragma unroll
    for (int i = 0; i < 16; ++i) W[i] = __expf(trans[STOP_TAG * 64 + 16 * q + i]);
  }

  const char* gb = (const char*)feats + (size_t)b * 262144 + (size_t)q * 64;
  const ptrdiff_t delta = (DIR == 0) ? 256 : -256;

  vf4 F[4][4];
  asm volatile("s_waitcnt vmcnt(0)" ::: "memory");
  #pragma unroll
  for (int p = 0; p < 4; ++p) {
    const char* a = gb + (size_t)((DIR == 0) ? p : 1023 - p) * 256;
    FIFO_LOAD(p, a);
  }
  const char* ap = gb + (size_t)((DIR == 0) ? 4 : 1019) * 256;

  float C = 0.f, zpend = 1.f;

  for (int bk = 0; bk < 32; ++bk) {
    #pragma unroll
    for (int u = 0; u < 16; ++u) {
      const int sl = u & 3;
      FIFO_WAIT12(sl);

      float e[16];
      #pragma unroll
      for (int v = 0; v < 4; ++v)
        #pragma unroll
        for (int i = 0; i < 4; ++i) e[v * 4 + i] = __expf(F[sl][v][i]);

      FIFO_LOAD(sl, ap);
      ap += delta;

      float P[16];
      #pragma unroll
      for (int i = 0; i < 16; ++i) P[i] = (DIR == 0) ? W[i] : W[i] * e[i];

      union { unsigned uu[4]; short8 s8; } B0, B1;
      B0.uu[0] = pk_bf16(P[0], P[1]);   B0.uu[1] = pk_bf16(P[2], P[3]);
      B0.uu[2] = pk_bf16(P[4], P[5]);   B0.uu[3] = pk_bf16(P[6], P[7]);
      B1.uu[0] = pk_bf16(P[8], P[9]);   B1.uu[1] = pk_bf16(P[10], P[11]);
      B1.uu[2] = pk_bf16(P[12], P[13]); B1.uu[3] = pk_bf16(P[14], P[15]);

      vf4 z4 = {0.f, 0.f, 0.f, 0.f};
      vf4 d0 = mfma16(A[0][0], B0.s8, z4);
      vf4 d1 = mfma16(A[1][0], B0.s8, z4);
      vf4 d2 = mfma16(A[2][0], B0.s8, z4);
      vf4 d3 = mfma16(A[3][0], B0.s8, z4);
      d0 = mfma16(A[0][1], B1.s8, d0);
      d1 = mfma16(A[1][1], B1.s8, d1);
      d2 = mfma16(A[2][1], B1.s8, d2);
      d3 = mfma16(A[3][1], B1.s8, d3);

      #pragma unroll
      for (int i = 0; i < 4; ++i) {
        W[i]      = (DIR == 0) ? d0[i] * e[i]      : d0[i];
        W[4 + i]  = (DIR == 0) ? d1[i] * e[4 + i]  : d1[i];
        W[8 + i]  = (DIR == 0) ? d2[i] * e[8 + i]  : d2[i];
        W[12 + i] = (DIR == 0) ? d3[i] * e[12 + i] : d3[i];
      }

      if ((u & 3) == 3) {
        float rz = __builtin_amdgcn_rcpf(zpend);
        C += __logf(zpend);
        #pragma unroll
        for (int i = 0; i < 16; ++i) W[i] *= rz;
        zpend = __shfl(W[0], col);
      }
    }
  }

  asm volatile("s_waitcnt vmcnt(0)"
               : "+v"(F[0][0]), "+v"(F[0][1]), "+v"(F[0][2]), "+v"(F[0][3]),
                 "+v"(F[1][0]), "+v"(F[1][1]), "+v"(F[1][2]), "+v"(F[1][3]),
                 "+v"(F[2][0]), "+v"(F[2][1]), "+v"(F[2][2]), "+v"(F[2][3]),
                 "+v"(F[3][0]), "+v"(F[3][1]), "+v"(F[3][2]), "+v"(F[3][3]) :: "memory");

  epilogue<DIR>(ws, W, C, g, lane, q, col);
}

// Masked fallback (general mask) — plain loads, per-step mask select (R4-verified).
template<int DIR>
__device__ __forceinline__ void chain_masked(const float* __restrict__ feats,
                                             const float* __restrict__ trans,
                                             const int* __restrict__ mask,
                                             float* __restrict__ ws, int g) {
  const int lane = threadIdx.x & 63;
  const int q = lane >> 4, col = lane & 15;
  const int b = g * 16 + col;

  short8 A[4][2];
  load_A<DIR>(trans, A, q, col);

  float W[16];
  float C = 0.f;
  if (DIR == 0) {
    #pragma unroll
    for (int i = 0; i < 16; ++i) W[i] = 0.f;
    if (q == 3) W[14] = 1.f;
  } else {
    #pragma unroll
    for (int i = 0; i < 16; ++i) W[i] = __expf(trans[STOP_TAG * 64 + 16 * q + i]);
  }

  const char* gb = (const char*)feats + (size_t)b * 262144 + (size_t)q * 64;
  vf4 cur[4];
  {
    size_t s0 = (DIR == 0) ? 0 : 1023;
    #pragma unroll
    for (int v = 0; v < 4; ++v)
      cur[v] = *(const vf4*)(gb + s0 * 256 + (size_t)v * 16);
  }

  for (int grp = 0; grp < 128; ++grp) {
    #pragma unroll
    for (int u = 0; u < 4; ++u) {
      const int j = grp * 4 + u;
      float e[16];
      #pragma unroll
      for (int v = 0; v < 4; ++v)
        #pragma unroll
        for (int i = 0; i < 4; ++i) e[v * 4 + i] = __expf(cur[v][i]);

      float P[16];
      #pragma unroll
      for (int i = 0; i < 16; ++i) P[i] = (DIR == 0) ? W[i] : W[i] * e[i];

      union { unsigned uu[4]; short8 s8; } B0, B1;
      B0.uu[0] = pk_bf16(P[0], P[1]);   B0.uu[1] = pk_bf16(P[2], P[3]);
      B0.uu[2] = pk_bf16(P[4], P[5]);   B0.uu[3] = pk_bf16(P[6], P[7]);
      B1.uu[0] = pk_bf16(P[8], P[9]);   B1.uu[1] = pk_bf16(P[10], P[11]);
      B1.uu[2] = pk_bf16(P[12], P[13]); B1.uu[3] = pk_bf16(P[14], P[15]);

      vf4 z4 = {0.f, 0.f, 0.f, 0.f};
      vf4 d0 = mfma16(A[0][0], B0.s8, z4);
      vf4 d1 = mfma16(A[1][0], B0.s8, z4);
      vf4 d2 = mfma16(A[2][0], B0.s8, z4);
      vf4 d3 = mfma16(A[3][0], B0.s8, z4);
      d0 = mfma16(A[0][1], B1.s8, d0);
      d1 = mfma16(A[1][1], B1.s8, d1);
      d2 = mfma16(A[2][1], B1.s8, d2);
      d3 = mfma16(A[3][1], B1.s8, d3);

      int sj = (DIR == 0) ? j : 1023 - j;
      int m = mask[b * 1024 + sj];
      int sn = (DIR == 0) ? (j + 1) : 1023 - (j + 1);
      #pragma unroll
      for (int v = 0; v < 4; ++v)
        cur[v] = *(const vf4*)(gb + (size_t)sn * 256 + (size_t)v * 16);

      #pragma unroll
      for (int i = 0; i < 4; ++i) {
        float n0 = (DIR == 0) ? d0[i] * e[i]      : d0[i];
        float n1 = (DIR == 0) ? d1[i] * e[4 + i]  : d1[i];
        float n2 = (DIR == 0) ? d2[i] * e[8 + i]  : d2[i];
        float n3 = (DIR == 0) ? d3[i] * e[12 + i] : d3[i];
        W[i]      = m ? n0 : W[i];
        W[4 + i]  = m ? n1 : W[4 + i];
        W[8 + i]  = m ? n2 : W[8 + i];
        W[12 + i] = m ? n3 : W[12 + i];
      }
    }
    float z = __shfl(W[0], col);
    float rz = __builtin_amdgcn_rcpf(z);
    C += __logf(z);
    #pragma unroll
    for (int i = 0; i < 16; ++i) W[i] *= rz;
  }
  epilogue<DIR>(ws, W, C, g, lane, q, col);
}

// Prepass: exp + transpose feats -> E' streaming layout. 8192 blocks x 256 thr.
// Each wave handles one (batch, 16-step block): 4KiB in, 4KiB out.
__global__ __launch_bounds__(256)
void crf_prepass(const float* __restrict__ feats, float* __restrict__ E) {
  const int blk = blockIdx.x;               // 0..8191
  const int b = blk >> 4;
  const int wave = threadIdx.x >> 6;
  const int lane = threadIdx.x & 63;
  const int sb = (blk & 15) * 4 + wave;     // 0..63
  const int st = lane >> 2, c = lane & 3;   // step-in-block, 16-float chunk
  const int s = sb * 16 + st;

  const float* src = feats + (size_t)b * 65536 + (size_t)s * 64 + (size_t)c * 16;
  vf4 v0 = *(const vf4*)(src);
  vf4 v1 = *(const vf4*)(src + 4);
  vf4 v2 = *(const vf4*)(src + 8);
  vf4 v3 = *(const vf4*)(src + 12);

  const int g = b >> 4, col = b & 15;
  const int dir = s >> 9;                   // s<512 -> 0
  const int j = dir ? (1023 - s) : s;       // bwd half stored reversed
  float* dst = E + ((size_t)(g * 2 + dir) * 512 + j) * 1024
               + (size_t)col * 64 + (size_t)c * 16;

  vf4 e0, e1, e2, e3;
  #pragma unroll
  for (int i = 0; i < 4; ++i) {
    e0[i] = __expf(v0[i]); e1[i] = __expf(v1[i]);
    e2[i] = __expf(v2[i]); e3[i] = __expf(v3[i]);
  }
  *(vf4*)(dst)      = e0;
  *(vf4*)(dst + 4)  = e1;
  *(vf4*)(dst + 8)  = e2;
  *(vf4*)(dst + 12) = e3;
}

// Blocks 0..63: chains (g=blk>>1, dir=blk&1). Blocks 64..575: gold score for batch blk-64.
template<int USE_E>
__global__ __launch_bounds__(64, 1)
void crf_main(const float* __restrict__ feats, const float* __restrict__ trans,
              const int* __restrict__ tags, const int* __restrict__ mask,
              float* __restrict__ ws, const float* __restrict__ E) {
  const int blk = blockIdx.x;
  if (blk < NCHAIN) {
    const int g = blk >> 1, dir = blk & 1;
    const int lane = threadIdx.x & 63;
    const int q = lane >> 4;
    const int col = lane & 15;
    const int b = g * 16 + col;
    const int sB = dir ? 512 : 0;
    int anyz = 0;
    for (int it = 0; it < 32; ++it) {
      int4 v = *(const int4*)(mask + b * 1024 + sB + (it * 4 + q) * 4);
      anyz |= (v.x == 0) | (v.y == 0) | (v.z == 0) | (v.w == 0);
    }
    bool allones = (__ballot(anyz != 0) == 0ull);
    if (allones) {
      if (USE_E) {
        if (dir == 0) chain_fast_x<0>(E, trans, ws, g);
        else          chain_fast_x<1>(E, trans, ws, g);
      } else {
        if (dir == 0) chain_fast<0>(feats, trans, ws, g);
        else          chain_fast<1>(feats, trans, ws, g);
      }
    } else {
      if (dir == 0) chain_masked<0>(feats, trans, mask, ws, g);
      else          chain_masked<1>(feats, trans, mask, ws, g);
    }
    (void)tags;
  } else {
    const int b = blk - NCHAIN;
    const int* tb = tags + b * SLEN;
    const int* mb = mask + b * SLEN;
    const float* fbg = feats + (size_t)b * 65536;
    float acc = 0.f, cnt = 0.f;
    const int t = threadIdx.x;
    for (int k = 0; k < 16; ++k) {
      int s = t + k * 64;
      int cur = tb[s];
      int prev = (s == 0) ? START_TAG : tb[s - 1];
      float m = (float)mb[s];
      acc += m * (fbg[s * 64 + cur] + trans[cur * 64 + prev]);
      cnt += m;
    }
    #pragma unroll
    for (int o = 1; o < 64; o <<= 1) {
      acc += __shfl_xor(acc, o);
      cnt += __shfl_xor(cnt, o);
    }
    if (t == 0) {
      int last_idx = (int)(cnt + 0.5f);
      int last_tag = (last_idx == 0) ? START_TAG : tb[last_idx - 1];
      ws[66560 + b] = acc + trans[STOP_TAG * 64 + last_tag];
    }
  }
}

__global__ __launch_bounds__(512)
void crf_reduce(const float* __restrict__ ws, float* __restrict__ out) {
  __shared__ float s[512];
  const int t = threadIdx.x;
  const int g = t >> 4, col = t & 15;
  const float* Wf = ws + (size_t)(2 * g) * 1024;
  const float* Wb = ws + (size_t)(2 * g + 1) * 1024;
  float P = 0.f;
  #pragma unroll
  for (int q = 0; q < 4; ++q)
    #pragma unroll
    for (int i = 0; i < 16; ++i)
      P += Wf[(q * 16 + col) * 16 + i] * Wb[(q * 16 + col) * 16 + i];
  float sc = ws[65536 + (2 * g) * 16 + col] + ws[65536 + (2 * g + 1) * 16 + col] + __logf(P);
  s[t] = sc - ws[66560 + t];
  __syncthreads();
  for (int off = 256; off > 0; off >>= 1) {
    if (t < off) s[t] += s[t + off];
    __syncthreads();
  }
  if (t == 0) out[0] = s[0] * (1.f / 512.f);
}

extern "C" void kernel_launch(void* const* d_in, const int* in_sizes, int n_in,
                              void* d_out, int out_size, void* d_ws, size_t ws_size,
                              hipStream_t stream) {
  const float* feats = (const float*)d_in[0];
  const float* trans = (const float*)d_in[1];
  const int* tags = (const int*)d_in[2];
  const int* mask = (const int*)d_in[3];
  float* ws = (float*)d_ws;
  float* out = (float*)d_out;

  if (ws_size >= WS_NEEDED) {
    float* E = ws + E_OFF_FLOATS;
    crf_prepass<<<8192, 256, 0, stream>>>(feats, E);
    crf_main<1><<<NCHAIN + BATCH, 64, 0, stream>>>(feats, trans, tags, mask, ws, E);
  } else {
    crf_main<0><<<NCHAIN + BATCH, 64, 0, stream>>>(feats, trans, tags, mask, ws, ws);
  }
  crf_reduce<<<1, 512, 0, stream>>>(ws, out);
}

// Round 5
// 333.119 us; speedup vs baseline: 1.1386x; 1.1386x over previous
//
#include <hip/hip_runtime.h>

#define START_TAG 62
#define STOP_TAG 63
#define BATCH 512
#define SLEN 1024
#define NCHAIN 64        // 32 groups x 2 directions

typedef float vf4 __attribute__((ext_vector_type(4)));
typedef short short8 __attribute__((ext_vector_type(8)));

// E' streaming layout, CHUNKED per step (4KiB per step):
//   float4 position within a step = k*64 + q*16 + col   (k=0..3, lane=q*16+col)
//   content at that position       = exp(feats[b = g*16+col][s][tags 16q+4k .. +4))
// so the chain's 4 loads per step (k=0..3) are each ONE contiguous 1KiB
// transaction with lane i reading bytes [i*16, i*16+16).
// dir=1 stored with j = 1023-s so BOTH directions stream strictly forward.
// Lives in ws at byte offset 1MiB.
#define E_OFF_FLOATS (1u << 18)                    // 1 MiB in floats
#define E_BYTES      134217728ull                  // 32*2*512*4096
#define WS_NEEDED    (1048576ull + E_BYTES + 65536ull)

__device__ __forceinline__ unsigned pk_bf16(float lo, float hi) {
  return __builtin_amdgcn_perm(__float_as_uint(hi), __float_as_uint(lo), 0x07060302u);
}
__device__ __forceinline__ short bf16_rne(float x) {
  unsigned u = __float_as_uint(x);
  u += 0x7FFFu + ((u >> 16) & 1u);
  return (short)(u >> 16);
}
__device__ __forceinline__ vf4 mfma16(short8 a, short8 b, vf4 c) {
  return __builtin_amdgcn_mfma_f32_16x16x32_bf16(a, b, c, 0, 0, 0);
}

// ---- A fragments: E (fwd) / E^T (bwd) in bf16, custom tag<->slot map (R3/R4-verified) ----
template<int DIR>
__device__ __forceinline__ void load_A(const float* __restrict__ trans, short8 A[4][2],
                                       int q, int col) {
  const int mrow = 16 * (col >> 2) + (col & 3);
  #pragma unroll
  for (int t = 0; t < 4; ++t) {
    #pragma unroll
    for (int c = 0; c < 2; ++c) {
      short8 a;
      #pragma unroll
      for (int j = 0; j < 8; ++j) {
        int R = mrow + 4 * t, K = 16 * q + 8 * c + j;
        float tv = (DIR == 0) ? trans[R * 64 + K] : trans[K * 64 + R];
        a[j] = bf16_rne(__expf(tv));
      }
      A[t][c] = a;
    }
  }
}

template<int DIR>
__device__ __forceinline__ void epilogue(float* __restrict__ ws, const float W[16],
                                         float C, int g, int lane, int q, int col) {
  float* slab = ws + (size_t)(g * 2 + DIR) * 1024;
  #pragma unroll
  for (int t4 = 0; t4 < 4; ++t4) {
    vf4 o = {W[t4 * 4], W[t4 * 4 + 1], W[t4 * 4 + 2], W[t4 * 4 + 3]};
    *(vf4*)(slab + lane * 16 + t4 * 4) = o;
  }
  if (q == 0) ws[65536 + (g * 2 + DIR) * 16 + col] = C;
}

// One recurrence step using pre-exp'd values Fs (the loaded words ARE exp(feat)).
// Fs[v][i] = exp(feat[tag 16q+4v+i]) — identical consumption mapping to the
// verified legacy path's e[v*4+i].
template<int DIR>
__device__ __forceinline__ void crf_step(const vf4 (&Fs)[4], const short8 (&A)[4][2],
                                         float (&W)[16]) {
  float P[16];
  #pragma unroll
  for (int t = 0; t < 4; ++t)
    #pragma unroll
    for (int i = 0; i < 4; ++i)
      P[t * 4 + i] = (DIR == 0) ? W[t * 4 + i] : W[t * 4 + i] * Fs[t][i];

  union { unsigned uu[4]; short8 s8; } B0, B1;
  B0.uu[0] = pk_bf16(P[0], P[1]);   B0.uu[1] = pk_bf16(P[2], P[3]);
  B0.uu[2] = pk_bf16(P[4], P[5]);   B0.uu[3] = pk_bf16(P[6], P[7]);
  B1.uu[0] = pk_bf16(P[8], P[9]);   B1.uu[1] = pk_bf16(P[10], P[11]);
  B1.uu[2] = pk_bf16(P[12], P[13]); B1.uu[3] = pk_bf16(P[14], P[15]);

  vf4 z4 = {0.f, 0.f, 0.f, 0.f};
  vf4 d0 = mfma16(A[0][0], B0.s8, z4);
  vf4 d1 = mfma16(A[1][0], B0.s8, z4);
  vf4 d2 = mfma16(A[2][0], B0.s8, z4);
  vf4 d3 = mfma16(A[3][0], B0.s8, z4);
  d0 = mfma16(A[0][1], B1.s8, d0);
  d1 = mfma16(A[1][1], B1.s8, d1);
  d2 = mfma16(A[2][1], B1.s8, d2);
  d3 = mfma16(A[3][1], B1.s8, d3);

  #pragma unroll
  for (int i = 0; i < 4; ++i) {
    W[i]      = (DIR == 0) ? d0[i] * Fs[0][i] : d0[i];
    W[4 + i]  = (DIR == 0) ? d1[i] * Fs[1][i] : d1[i];
    W[8 + i]  = (DIR == 0) ? d2[i] * Fs[2][i] : d2[i];
    W[12 + i] = (DIR == 0) ? d3[i] * Fs[3][i] : d3[i];
  }
}

// ---------------------------------------------------------------------------
// Streaming fast path, NO inline asm. Register FIFO depth 8, pipeline depth
// structurally locked by sched_barrier(0): each step is its own scheduling
// region, so the step-(j+8) loads issued in step j cannot sink toward their
// uses (R3 failure mode) and later loads cannot hoist. The compiler's waitcnt
// pass emits exact vmcnt(28)-style waits — correct by construction.
// ---------------------------------------------------------------------------
template<int DIR>
__device__ __forceinline__ void chain_fast_x(const float* E,
                                             const float* __restrict__ trans,
                                             float* __restrict__ ws, int g) {
  const int lane = threadIdx.x & 63;
  const int q = lane >> 4, col = lane & 15;

  short8 A[4][2];
  load_A<DIR>(trans, A, q, col);

  float W[16];
  if (DIR == 0) {
    #pragma unroll
    for (int i = 0; i < 16; ++i) W[i] = 0.f;
    if (q == 3) W[14] = 1.f;                    // true tag 62 = START
  } else {
    #pragma unroll
    for (int i = 0; i < 16; ++i) W[i] = __expf(trans[STOP_TAG * 64 + 16 * q + i]);
  }

  // per-lane base: this chain's stream + lane offset; +256 float4s per step
  const vf4* sp = (const vf4*)E + (((size_t)(g * 2 + DIR) * 512) << 8)
                  + (q << 4) + col;

  vf4 F[8][4];
  #pragma unroll
  for (int p = 0; p < 8; ++p)
    #pragma unroll
    for (int k = 0; k < 4; ++k)
      F[p][k] = sp[(size_t)p * 256 + k * 64];   // steps 0..7

  float C = 0.f, zpend = 1.f;

  // steps 0..503; each step prefetches step j+8 (8..511) into its slot
  for (int bk = 0; bk < 63; ++bk) {
    #pragma unroll
    for (int u = 0; u < 8; ++u) {
      crf_step<DIR>(F[u], A, W);
      const int jn = bk * 8 + u + 8;            // <= 511, always in-bounds
      #pragma unroll
      for (int k = 0; k < 4; ++k)
        F[u][k] = sp[(size_t)jn * 256 + k * 64];
      if ((u & 3) == 3) {
        // pipelined renorm (R5-verified): apply z measured 4 steps ago
        float rz = __builtin_amdgcn_rcpf(zpend);
        C += __logf(zpend);
        #pragma unroll
        for (int i = 0; i < 16; ++i) W[i] *= rz;
        zpend = __shfl(W[0], col);              // true-tag-0 weight (> 0)
      }
      __builtin_amdgcn_sched_barrier(0);        // lock pipeline depth at 8
    }
  }

  // steps 504..511: slots already in flight/resident; compiler inserts the
  // exact waits before each use. Pure compute tail, no loads.
  #pragma unroll
  for (int u = 0; u < 8; ++u) {
    crf_step<DIR>(F[u], A, W);
    if ((u & 3) == 3) {
      float rz = __builtin_amdgcn_rcpf(zpend);
      C += __logf(zpend);
      #pragma unroll
      for (int i = 0; i < 16; ++i) W[i] *= rz;
      zpend = __shfl(W[0], col);
    }
  }

  epilogue<DIR>(ws, W, C, g, lane, q, col);
}

// Masked path (general mask) — plain loads, per-step mask select (R4-verified).
// Also serves as the small-workspace fallback (correct for all-ones masks).
template<int DIR>
__device__ __forceinline__ void chain_masked(const float* __restrict__ feats,
                                             const float* __restrict__ trans,
                                             const int* __restrict__ mask,
                                             float* __restrict__ ws, int g) {
  const int lane = threadIdx.x & 63;
  const int q = lane >> 4, col = lane & 15;
  const int b = g * 16 + col;

  short8 A[4][2];
  load_A<DIR>(trans, A, q, col);

  float W[16];
  float C = 0.f;
  if (DIR == 0) {
    #pragma unroll
    for (int i = 0; i < 16; ++i) W[i] = 0.f;
    if (q == 3) W[14] = 1.f;
  } else {
    #pragma unroll
    for (int i = 0; i < 16; ++i) W[i] = __expf(trans[STOP_TAG * 64 + 16 * q + i]);
  }

  const char* gb = (const char*)feats + (size_t)b * 262144 + (size_t)q * 64;
  vf4 cur[4];
  {
    size_t s0 = (DIR == 0) ? 0 : 1023;
    #pragma unroll
    for (int v = 0; v < 4; ++v)
      cur[v] = *(const vf4*)(gb + s0 * 256 + (size_t)v * 16);
  }

  for (int grp = 0; grp < 128; ++grp) {
    #pragma unroll
    for (int u = 0; u < 4; ++u) {
      const int j = grp * 4 + u;
      float e[16];
      #pragma unroll
      for (int v = 0; v < 4; ++v)
        #pragma unroll
        for (int i = 0; i < 4; ++i) e[v * 4 + i] = __expf(cur[v][i]);

      float P[16];
      #pragma unroll
      for (int i = 0; i < 16; ++i) P[i] = (DIR == 0) ? W[i] : W[i] * e[i];

      union { unsigned uu[4]; short8 s8; } B0, B1;
      B0.uu[0] = pk_bf16(P[0], P[1]);   B0.uu[1] = pk_bf16(P[2], P[3]);
      B0.uu[2] = pk_bf16(P[4], P[5]);   B0.uu[3] = pk_bf16(P[6], P[7]);
      B1.uu[0] = pk_bf16(P[8], P[9]);   B1.uu[1] = pk_bf16(P[10], P[11]);
      B1.uu[2] = pk_bf16(P[12], P[13]); B1.uu[3] = pk_bf16(P[14], P[15]);

      vf4 z4 = {0.f, 0.f, 0.f, 0.f};
      vf4 d0 = mfma16(A[0][0], B0.s8, z4);
      vf4 d1 = mfma16(A[1][0], B0.s8, z4);
      vf4 d2 = mfma16(A[2][0], B0.s8, z4);
      vf4 d3 = mfma16(A[3][0], B0.s8, z4);
      d0 = mfma16(A[0][1], B1.s8, d0);
      d1 = mfma16(A[1][1], B1.s8, d1);
      d2 = mfma16(A[2][1], B1.s8, d2);
      d3 = mfma16(A[3][1], B1.s8, d3);

      int sj = (DIR == 0) ? j : 1023 - j;
      int m = mask[b * 1024 + sj];
      int sn = (DIR == 0) ? (j + 1) : 1023 - (j + 1);
      #pragma unroll
      for (int v = 0; v < 4; ++v)
        cur[v] = *(const vf4*)(gb + (size_t)sn * 256 + (size_t)v * 16);

      #pragma unroll
      for (int i = 0; i < 4; ++i) {
        float n0 = (DIR == 0) ? d0[i] * e[i]      : d0[i];
        float n1 = (DIR == 0) ? d1[i] * e[4 + i]  : d1[i];
        float n2 = (DIR == 0) ? d2[i] * e[8 + i]  : d2[i];
        float n3 = (DIR == 0) ? d3[i] * e[12 + i] : d3[i];
        W[i]      = m ? n0 : W[i];
        W[4 + i]  = m ? n1 : W[4 + i];
        W[8 + i]  = m ? n2 : W[8 + i];
        W[12 + i] = m ? n3 : W[12 + i];
      }
    }
    float z = __shfl(W[0], col);
    float rz = __builtin_amdgcn_rcpf(z);
    C += __logf(z);
    #pragma unroll
    for (int i = 0; i < 16; ++i) W[i] *= rz;
  }
  epilogue<DIR>(ws, W, C, g, lane, q, col);
}

// Prepass: exp + transpose feats -> chunked E'. One thread = one float4.
// Wave reads 4 x 256B contiguous rows; writes 16 x 64B segments (one 4KB step
// region per 4 waves). No LDS, no sync.
__global__ __launch_bounds__(256)
void crf_prepass(const float* __restrict__ feats, float* __restrict__ E) {
  const unsigned o = blockIdx.x * 256u + threadIdx.x;   // 0 .. 2^23-1
  const unsigned t    = o & 15u;                        // tag4 index (tags 4t..4t+4)
  const unsigned col  = (o >> 4) & 15u;
  const unsigned j    = (o >> 8) & 511u;
  const unsigned gd   = o >> 17;                        // g*2+dir
  const unsigned dir  = gd & 1u;
  const unsigned s    = dir ? (1023u - j) : j;          // bwd half stored reversed
  const unsigned b    = (gd >> 1) * 16u + col;

  vf4 v = ((const vf4*)feats)[(size_t)b * 16384 + (size_t)s * 16 + t];
  vf4 e;
  #pragma unroll
  for (int i = 0; i < 4; ++i) e[i] = __expf(v[i]);

  // chunked position: k = t&3, q = t>>2  ->  k*64 + q*16 + col
  const size_t dst = (((size_t)gd * 512 + j) << 8)
                     + ((t & 3u) << 6) + ((t >> 2) << 4) + col;
  ((vf4*)E)[dst] = e;
}

// Blocks 0..63: chains (g=blk>>1, dir=blk&1). Blocks 64..575: gold score for batch blk-64.
template<int USE_E>
__global__ __launch_bounds__(64, 1)
void crf_main(const float* __restrict__ feats, const float* __restrict__ trans,
              const int* __restrict__ tags, const int* __restrict__ mask,
              float* __restrict__ ws, const float* E) {
  const int blk = blockIdx.x;
  if (blk < NCHAIN) {
    const int g = blk >> 1, dir = blk & 1;
    const int lane = threadIdx.x & 63;
    const int q = lane >> 4;
    const int col = lane & 15;
    const int b = g * 16 + col;
    const int sB = dir ? 512 : 0;
    int anyz = 0;
    for (int it = 0; it < 32; ++it) {
      int4 v = *(const int4*)(mask + b * 1024 + sB + (it * 4 + q) * 4);
      anyz |= (v.x == 0) | (v.y == 0) | (v.z == 0) | (v.w == 0);
    }
    bool allones = (__ballot(anyz != 0) == 0ull);
    if (USE_E && allones) {
      if (dir == 0) chain_fast_x<0>(E, trans, ws, g);
      else          chain_fast_x<1>(E, trans, ws, g);
    } else {
      if (dir == 0) chain_masked<0>(feats, trans, mask, ws, g);
      else          chain_masked<1>(feats, trans, mask, ws, g);
    }
    (void)tags;
  } else {
    const int b = blk - NCHAIN;
    const int* tb = tags + b * SLEN;
    const int* mb = mask + b * SLEN;
    const float* fbg = feats + (size_t)b * 65536;
    float acc = 0.f, cnt = 0.f;
    const int t = threadIdx.x;
    for (int k = 0; k < 16; ++k) {
      int s = t + k * 64;
      int cur = tb[s];
      int prev = (s == 0) ? START_TAG : tb[s - 1];
      float m = (float)mb[s];
      acc += m * (fbg[s * 64 + cur] + trans[cur * 64 + prev]);
      cnt += m;
    }
    #pragma unroll
    for (int o = 1; o < 64; o <<= 1) {
      acc += __shfl_xor(acc, o);
      cnt += __shfl_xor(cnt, o);
    }
    if (t == 0) {
      int last_idx = (int)(cnt + 0.5f);
      int last_tag = (last_idx == 0) ? START_TAG : tb[last_idx - 1];
      ws[66560 + b] = acc + trans[STOP_TAG * 64 + last_tag];
    }
  }
}

__global__ __launch_bounds__(512)
void crf_reduce(const float* __restrict__ ws, float* __restrict__ out) {
  __shared__ float s[512];
  const int t = threadIdx.x;
  const int g = t >> 4, col = t & 15;
  const float* Wf = ws + (size_t)(2 * g) * 1024;
  const float* Wb = ws + (size_t)(2 * g + 1) * 1024;
  float P = 0.f;
  #pragma unroll
  for (int q = 0; q < 4; ++q)
    #pragma unroll
    for (int i = 0; i < 16; ++i)
      P += Wf[(q * 16 + col) * 16 + i] * Wb[(q * 16 + col) * 16 + i];
  float sc = ws[65536 + (2 * g) * 16 + col] + ws[65536 + (2 * g + 1) * 16 + col] + __logf(P);
  s[t] = sc - ws[66560 + t];
  __syncthreads();
  for (int off = 256; off > 0; off >>= 1) {
    if (t < off) s[t] += s[t + off];
    __syncthreads();
  }
  if (t == 0) out[0] = s[0] * (1.f / 512.f);
}

extern "C" void kernel_launch(void* const* d_in, const int* in_sizes, int n_in,
                              void* d_out, int out_size, void* d_ws, size_t ws_size,
                              hipStream_t stream) {
  const float* feats = (const float*)d_in[0];
  const float* trans = (const float*)d_in[1];
  const int* tags = (const int*)d_in[2];
  const int* mask = (const int*)d_in[3];
  float* ws = (float*)d_ws;
  float* out = (float*)d_out;

  if (ws_size >= WS_NEEDED) {
    float* E = ws + E_OFF_FLOATS;
    crf_prepass<<<32768, 256, 0, stream>>>(feats, E);
    crf_main<1><<<NCHAIN + BATCH, 64, 0, stream>>>(feats, trans, tags, mask, ws, E);
  } else {
    crf_main<0><<<NCHAIN + BATCH, 64, 0, stream>>>(feats, trans, tags, mask, ws, ws);
  }
  crf_reduce<<<1, 512, 0, stream>>>(ws, out);
}

// Round 7
// 308.871 us; speedup vs baseline: 1.2280x; 1.0785x over previous
//
#include <hip/hip_runtime.h>

#define START_TAG 62
#define STOP_TAG 63
#define BATCH 512
#define SLEN 1024
#define NCHAIN 64        // 32 groups x 2 directions

typedef float vf4 __attribute__((ext_vector_type(4)));
typedef short short8 __attribute__((ext_vector_type(8)));

// E2 streaming layout (bf16, 2KiB per step):
//   step block = [lane:64][32B]; lane l=(q*16+col) holds tags 16q..16q+15 as
//   16 bf16 (RNE) of exp(feats[b=g*16+col][s][tag]), dword = (tag_odd<<16)|tag_even.
//   dir=1 stored with j = 1023-s so BOTH directions stream strictly forward.
// 64MiB total -> fully L3-resident during the chain phase.
// Lives in ws at byte offset 1MiB.
#define E_BYTES      67108864ull                   // 64*512*2048
#define WS_NEEDED    (1048576ull + E_BYTES + 65536ull)

__device__ __forceinline__ unsigned pk_bf16(float lo, float hi) {
  return __builtin_amdgcn_perm(__float_as_uint(hi), __float_as_uint(lo), 0x07060302u);
}
__device__ __forceinline__ short bf16_rne(float x) {
  unsigned u = __float_as_uint(x);
  u += 0x7FFFu + ((u >> 16) & 1u);
  return (short)(u >> 16);
}
__device__ __forceinline__ unsigned pk2_rne(float lo, float hi) {
  return ((unsigned)(unsigned short)bf16_rne(hi) << 16)
       | (unsigned)(unsigned short)bf16_rne(lo);
}
__device__ __forceinline__ vf4 mfma16(short8 a, short8 b, vf4 c) {
  return __builtin_amdgcn_mfma_f32_16x16x32_bf16(a, b, c, 0, 0, 0);
}

// ---- A fragments: E (fwd) / E^T (bwd) in bf16, custom tag<->slot map (R3/R4-verified) ----
template<int DIR>
__device__ __forceinline__ void load_A(const float* __restrict__ trans, short8 A[4][2],
                                       int q, int col) {
  const int mrow = 16 * (col >> 2) + (col & 3);
  #pragma unroll
  for (int t = 0; t < 4; ++t) {
    #pragma unroll
    for (int c = 0; c < 2; ++c) {
      short8 a;
      #pragma unroll
      for (int j = 0; j < 8; ++j) {
        int R = mrow + 4 * t, K = 16 * q + 8 * c + j;
        float tv = (DIR == 0) ? trans[R * 64 + K] : trans[K * 64 + R];
        a[j] = bf16_rne(__expf(tv));
      }
      A[t][c] = a;
    }
  }
}

template<int DIR>
__device__ __forceinline__ void epilogue(float* __restrict__ ws, const float W[16],
                                         float C, int g, int lane, int q, int col) {
  float* slab = ws + (size_t)(g * 2 + DIR) * 1024;
  #pragma unroll
  for (int t4 = 0; t4 < 4; ++t4) {
    vf4 o = {W[t4 * 4], W[t4 * 4 + 1], W[t4 * 4 + 2], W[t4 * 4 + 3]};
    *(vf4*)(slab + lane * 16 + t4 * 4) = o;
  }
  if (q == 0) ws[65536 + (g * 2 + DIR) * 16 + col] = C;
}

// One recurrence step: Fs[t][i] = e[4t+i] = exp(feat[tag 16q+4t+i]) as f32.
// Bit-identical consumption mapping to the verified legacy path.
template<int DIR>
__device__ __forceinline__ void crf_step(const vf4 (&Fs)[4], const short8 (&A)[4][2],
                                         float (&W)[16]) {
  float P[16];
  #pragma unroll
  for (int t = 0; t < 4; ++t)
    #pragma unroll
    for (int i = 0; i < 4; ++i)
      P[t * 4 + i] = (DIR == 0) ? W[t * 4 + i] : W[t * 4 + i] * Fs[t][i];

  union { unsigned uu[4]; short8 s8; } B0, B1;
  B0.uu[0] = pk_bf16(P[0], P[1]);   B0.uu[1] = pk_bf16(P[2], P[3]);
  B0.uu[2] = pk_bf16(P[4], P[5]);   B0.uu[3] = pk_bf16(P[6], P[7]);
  B1.uu[0] = pk_bf16(P[8], P[9]);   B1.uu[1] = pk_bf16(P[10], P[11]);
  B1.uu[2] = pk_bf16(P[12], P[13]); B1.uu[3] = pk_bf16(P[14], P[15]);

  vf4 z4 = {0.f, 0.f, 0.f, 0.f};
  vf4 d0 = mfma16(A[0][0], B0.s8, z4);
  vf4 d1 = mfma16(A[1][0], B0.s8, z4);
  vf4 d2 = mfma16(A[2][0], B0.s8, z4);
  vf4 d3 = mfma16(A[3][0], B0.s8, z4);
  d0 = mfma16(A[0][1], B1.s8, d0);
  d1 = mfma16(A[1][1], B1.s8, d1);
  d2 = mfma16(A[2][1], B1.s8, d2);
  d3 = mfma16(A[3][1], B1.s8, d3);

  #pragma unroll
  for (int i = 0; i < 4; ++i) {
    W[i]      = (DIR == 0) ? d0[i] * Fs[0][i] : d0[i];
    W[4 + i]  = (DIR == 0) ? d1[i] * Fs[1][i] : d1[i];
    W[8 + i]  = (DIR == 0) ? d2[i] * Fs[2][i] : d2[i];
    W[12 + i] = (DIR == 0) ? d3[i] * Fs[3][i] : d3[i];
  }
}

// Unpack one step's 8 bf16-pair dwords (2 vf4) into Fs[4] f32 fragments:
// e[8h+2i] = lo(bf16)<<16, e[8h+2i+1] = hi&0xFFFF0000; Fs[j>>2][j&3] = e[j].
__device__ __forceinline__ void unpack_e(const vf4 (&Fh)[2], vf4 (&Es)[4]) {
  #pragma unroll
  for (int h = 0; h < 2; ++h)
    #pragma unroll
    for (int i = 0; i < 4; ++i) {
      unsigned d = __float_as_uint(Fh[h][i]);
      Es[2 * h + (i >> 1)][2 * (i & 1) + 0] = __uint_as_float(d << 16);
      Es[2 * h + (i >> 1)][2 * (i & 1) + 1] = __uint_as_float(d & 0xFFFF0000u);
    }
}

// ---------------------------------------------------------------------------
// Streaming fast path (NO inline asm): bf16 E2 stream, 2KiB/step, register
// FIFO depth 8 with one scheduling region per step (sched_barrier(0) locks the
// prefetch distance — R5-verified structure). E2 is L3-resident.
// ---------------------------------------------------------------------------
template<int DIR>
__device__ __forceinline__ void chain_fast_x(const char* E2,
                                             const float* __restrict__ trans,
                                             float* __restrict__ ws, int g) {
  const int lane = threadIdx.x & 63;
  const int q = lane >> 4, col = lane & 15;

  short8 A[4][2];
  load_A<DIR>(trans, A, q, col);

  float W[16];
  if (DIR == 0) {
    #pragma unroll
    for (int i = 0; i < 16; ++i) W[i] = 0.f;
    if (q == 3) W[14] = 1.f;                    // true tag 62 = START
  } else {
    #pragma unroll
    for (int i = 0; i < 16; ++i) W[i] = __expf(trans[STOP_TAG * 64 + 16 * q + i]);
  }

  // per-lane base into this chain's stream; +2048B per step
  const char* ap = E2 + (((size_t)(g * 2 + DIR) * 512) << 11) + (size_t)lane * 32;

  vf4 F[8][2];
  #pragma unroll
  for (int p = 0; p < 8; ++p) {
    F[p][0] = *(const vf4*)(ap + (size_t)p * 2048);
    F[p][1] = *(const vf4*)(ap + (size_t)p * 2048 + 16);
  }

  float C = 0.f, zpend = 1.f;

  // steps 0..503; each step prefetches step j+8 (8..511) into its slot
  for (int bk = 0; bk < 63; ++bk) {
    #pragma unroll
    for (int u = 0; u < 8; ++u) {
      vf4 Es[4];
      unpack_e(F[u], Es);
      crf_step<DIR>(Es, A, W);
      const int jn = bk * 8 + u + 8;            // <= 511, always in-bounds
      F[u][0] = *(const vf4*)(ap + (size_t)jn * 2048);
      F[u][1] = *(const vf4*)(ap + (size_t)jn * 2048 + 16);
      if ((u & 3) == 3) {
        // pipelined renorm (R5-verified): apply z measured 4 steps ago
        float rz = __builtin_amdgcn_rcpf(zpend);
        C += __logf(zpend);
        #pragma unroll
        for (int i = 0; i < 16; ++i) W[i] *= rz;
        zpend = __shfl(W[0], col);              // true-tag-0 weight (> 0)
      }
      __builtin_amdgcn_sched_barrier(0);        // lock pipeline depth at 8
    }
  }

  // steps 504..511: slots already loaded/in flight; pure compute tail
  #pragma unroll
  for (int u = 0; u < 8; ++u) {
    vf4 Es[4];
    unpack_e(F[u], Es);
    crf_step<DIR>(Es, A, W);
    if ((u & 3) == 3) {
      float rz = __builtin_amdgcn_rcpf(zpend);
      C += __logf(zpend);
      #pragma unroll
      for (int i = 0; i < 16; ++i) W[i] *= rz;
      zpend = __shfl(W[0], col);
    }
  }

  epilogue<DIR>(ws, W, C, g, lane, q, col);
}

// Masked path (general mask) — plain loads, per-step mask select (R4-verified).
// Also serves as the small-workspace fallback (correct for all-ones masks).
template<int DIR>
__device__ __forceinline__ void chain_masked(const float* __restrict__ feats,
                                             const float* __restrict__ trans,
                                             const int* __restrict__ mask,
                                             float* __restrict__ ws, int g) {
  const int lane = threadIdx.x & 63;
  const int q = lane >> 4, col = lane & 15;
  const int b = g * 16 + col;

  short8 A[4][2];
  load_A<DIR>(trans, A, q, col);

  float W[16];
  float C = 0.f;
  if (DIR == 0) {
    #pragma unroll
    for (int i = 0; i < 16; ++i) W[i] = 0.f;
    if (q == 3) W[14] = 1.f;
  } else {
    #pragma unroll
    for (int i = 0; i < 16; ++i) W[i] = __expf(trans[STOP_TAG * 64 + 16 * q + i]);
  }

  const char* gb = (const char*)feats + (size_t)b * 262144 + (size_t)q * 64;
  vf4 cur[4];
  {
    size_t s0 = (DIR == 0) ? 0 : 1023;
    #pragma unroll
    for (int v = 0; v < 4; ++v)
      cur[v] = *(const vf4*)(gb + s0 * 256 + (size_t)v * 16);
  }

  for (int grp = 0; grp < 128; ++grp) {
    #pragma unroll
    for (int u = 0; u < 4; ++u) {
      const int j = grp * 4 + u;
      float e[16];
      #pragma unroll
      for (int v = 0; v < 4; ++v)
        #pragma unroll
        for (int i = 0; i < 4; ++i) e[v * 4 + i] = __expf(cur[v][i]);

      float P[16];
      #pragma unroll
      for (int i = 0; i < 16; ++i) P[i] = (DIR == 0) ? W[i] : W[i] * e[i];

      union { unsigned uu[4]; short8 s8; } B0, B1;
      B0.uu[0] = pk_bf16(P[0], P[1]);   B0.uu[1] = pk_bf16(P[2], P[3]);
      B0.uu[2] = pk_bf16(P[4], P[5]);   B0.uu[3] = pk_bf16(P[6], P[7]);
      B1.uu[0] = pk_bf16(P[8], P[9]);   B1.uu[1] = pk_bf16(P[10], P[11]);
      B1.uu[2] = pk_bf16(P[12], P[13]); B1.uu[3] = pk_bf16(P[14], P[15]);

      vf4 z4 = {0.f, 0.f, 0.f, 0.f};
      vf4 d0 = mfma16(A[0][0], B0.s8, z4);
      vf4 d1 = mfma16(A[1][0], B0.s8, z4);
      vf4 d2 = mfma16(A[2][0], B0.s8, z4);
      vf4 d3 = mfma16(A[3][0], B0.s8, z4);
      d0 = mfma16(A[0][1], B1.s8, d0);
      d1 = mfma16(A[1][1], B1.s8, d1);
      d2 = mfma16(A[2][1], B1.s8, d2);
      d3 = mfma16(A[3][1], B1.s8, d3);

      int sj = (DIR == 0) ? j : 1023 - j;
      int m = mask[b * 1024 + sj];
      int sn = (DIR == 0) ? (j + 1) : 1023 - (j + 1);
      #pragma unroll
      for (int v = 0; v < 4; ++v)
        cur[v] = *(const vf4*)(gb + (size_t)sn * 256 + (size_t)v * 16);

      #pragma unroll
      for (int i = 0; i < 4; ++i) {
        float n0 = (DIR == 0) ? d0[i] * e[i]      : d0[i];
        float n1 = (DIR == 0) ? d1[i] * e[4 + i]  : d1[i];
        float n2 = (DIR == 0) ? d2[i] * e[8 + i]  : d2[i];
        float n3 = (DIR == 0) ? d3[i] * e[12 + i] : d3[i];
        W[i]      = m ? n0 : W[i];
        W[4 + i]  = m ? n1 : W[4 + i];
        W[8 + i]  = m ? n2 : W[8 + i];
        W[12 + i] = m ? n3 : W[12 + i];
      }
    }
    float z = __shfl(W[0], col);
    float rz = __builtin_amdgcn_rcpf(z);
    C += __logf(z);
    #pragma unroll
    for (int i = 0; i < 16; ++i) W[i] *= rz;
  }
  epilogue<DIR>(ws, W, C, g, lane, q, col);
}

// Prepass: exp + transpose + bf16-pack feats -> E2. One thread = one 16B unit;
// GLOBAL write index == thread index (whole grid writes linearly, full lines).
// unit u: c=u&1, l=(u>>1)&63, j=(u>>7)&511, gd=u>>16; thread reads 8 floats
// (32B contiguous) and writes 8 bf16 (16B).
__global__ __launch_bounds__(256)
void crf_prepass(const float* __restrict__ feats, int4* __restrict__ E2) {
  const unsigned u = blockIdx.x * 256u + threadIdx.x;   // < 2^22
  const unsigned c   = u & 1u;
  const unsigned l   = (u >> 1) & 63u;
  const unsigned j   = (u >> 7) & 511u;
  const unsigned gd  = u >> 16;                         // g*2+dir
  const unsigned dir = gd & 1u;
  const unsigned q   = l >> 4, col = l & 15u;
  const unsigned s   = dir ? (1023u - j) : j;           // bwd half stored reversed
  const unsigned b   = (gd >> 1) * 16u + col;

  const vf4* src = (const vf4*)feats + (size_t)b * 16384 + (size_t)s * 16
                   + 4u * q + 2u * c;                   // floats 16q+8c .. +8
  vf4 v0 = src[0], v1 = src[1];
  float e[8];
  #pragma unroll
  for (int i = 0; i < 4; ++i) { e[i] = __expf(v0[i]); e[4 + i] = __expf(v1[i]); }

  int4 o;
  o.x = (int)pk2_rne(e[0], e[1]);
  o.y = (int)pk2_rne(e[2], e[3]);
  o.z = (int)pk2_rne(e[4], e[5]);
  o.w = (int)pk2_rne(e[6], e[7]);
  E2[u] = o;
}

// Blocks 0..63: chains (g=blk>>1, dir=blk&1). Blocks 64..575: gold score for batch blk-64.
template<int USE_E>
__global__ __launch_bounds__(64, 1)
void crf_main(const float* __restrict__ feats, const float* __restrict__ trans,
              const int* __restrict__ tags, const int* __restrict__ mask,
              float* __restrict__ ws, const char* E2) {
  const int blk = blockIdx.x;
  if (blk < NCHAIN) {
    const int g = blk >> 1, dir = blk & 1;
    const int lane = threadIdx.x & 63;
    const int q = lane >> 4;
    const int col = lane & 15;
    const int b = g * 16 + col;
    const int sB = dir ? 512 : 0;
    int anyz = 0;
    for (int it = 0; it < 32; ++it) {
      int4 v = *(const int4*)(mask + b * 1024 + sB + (it * 4 + q) * 4);
      anyz |= (v.x == 0) | (v.y == 0) | (v.z == 0) | (v.w == 0);
    }
    bool allones = (__ballot(anyz != 0) == 0ull);
    if (USE_E && allones) {
      if (dir == 0) chain_fast_x<0>(E2, trans, ws, g);
      else          chain_fast_x<1>(E2, trans, ws, g);
    } else {
      if (dir == 0) chain_masked<0>(feats, trans, mask, ws, g);
      else          chain_masked<1>(feats, trans, mask, ws, g);
    }
    (void)tags;
  } else {
    const int b = blk - NCHAIN;
    const int* tb = tags + b * SLEN;
    const int* mb = mask + b * SLEN;
    const float* fbg = feats + (size_t)b * 65536;
    float acc = 0.f, cnt = 0.f;
    const int t = threadIdx.x;
    for (int k = 0; k < 16; ++k) {
      int s = t + k * 64;
      int cur = tb[s];
      int prev = (s == 0) ? START_TAG : tb[s - 1];
      float m = (float)mb[s];
      acc += m * (fbg[s * 64 + cur] + trans[cur * 64 + prev]);
      cnt += m;
    }
    #pragma unroll
    for (int o = 1; o < 64; o <<= 1) {
      acc += __shfl_xor(acc, o);
      cnt += __shfl_xor(cnt, o);
    }
    if (t == 0) {
      int last_idx = (int)(cnt + 0.5f);
      int last_tag = (last_idx == 0) ? START_TAG : tb[last_idx - 1];
      ws[66560 + b] = acc + trans[STOP_TAG * 64 + last_tag];
    }
  }
}

__global__ __launch_bounds__(512)
void crf_reduce(const float* __restrict__ ws, float* __restrict__ out) {
  __shared__ float s[512];
  const int t = threadIdx.x;
  const int g = t >> 4, col = t & 15;
  const float* Wf = ws + (size_t)(2 * g) * 1024;
  const float* Wb = ws + (size_t)(2 * g + 1) * 1024;
  float P = 0.f;
  #pragma unroll
  for (int q = 0; q < 4; ++q)
    #pragma unroll
    for (int i = 0; i < 16; ++i)
      P += Wf[(q * 16 + col) * 16 + i] * Wb[(q * 16 + col) * 16 + i];
  float sc = ws[65536 + (2 * g) * 16 + col] + ws[65536 + (2 * g + 1) * 16 + col] + __logf(P);
  s[t] = sc - ws[66560 + t];
  __syncthreads();
  for (int off = 256; off > 0; off >>= 1) {
    if (t < off) s[t] += s[t + off];
    __syncthreads();
  }
  if (t == 0) out[0] = s[0] * (1.f / 512.f);
}

extern "C" void kernel_launch(void* const* d_in, const int* in_sizes, int n_in,
                              void* d_out, int out_size, void* d_ws, size_t ws_size,
                              hipStream_t stream) {
  const float* feats = (const float*)d_in[0];
  const float* trans = (const float*)d_in[1];
  const int* tags = (const int*)d_in[2];
  const int* mask = (const int*)d_in[3];
  float* ws = (float*)d_ws;
  float* out = (float*)d_out;

  if (ws_size >= WS_NEEDED) {
    char* E2 = (char*)ws + (1u << 20);
    crf_prepass<<<16384, 256, 0, stream>>>(feats, (int4*)E2);
    crf_main<1><<<NCHAIN + BATCH, 64, 0, stream>>>(feats, trans, tags, mask, ws, E2);
  } else {
    crf_main<0><<<NCHAIN + BATCH, 64, 0, stream>>>(feats, trans, tags, mask, ws,
                                                   (const char*)ws);
  }
  crf_reduce<<<1, 512, 0, stream>>>(ws, out);
}

// Round 8
// 304.709 us; speedup vs baseline: 1.2448x; 1.0137x over previous
//
#include <hip/hip_runtime.h>

#define START_TAG 62
#define STOP_TAG 63
#define BATCH 512
#define SLEN 1024
#define NCHAIN 64        // 32 groups x 2 directions

typedef float vf4 __attribute__((ext_vector_type(4)));
typedef short short8 __attribute__((ext_vector_type(8)));

__device__ __forceinline__ unsigned pk_bf16(float lo, float hi) {
  return __builtin_amdgcn_perm(__float_as_uint(hi), __float_as_uint(lo), 0x07060302u);
}
__device__ __forceinline__ short bf16_rne(float x) {
  unsigned u = __float_as_uint(x);
  u += 0x7FFFu + ((u >> 16) & 1u);
  return (short)(u >> 16);
}
__device__ __forceinline__ vf4 mfma16(short8 a, short8 b, vf4 c) {
  return __builtin_amdgcn_mfma_f32_16x16x32_bf16(a, b, c, 0, 0, 0);
}

// ---- A fragments: E (fwd) / E^T (bwd) in bf16, custom tag<->slot map (R3/R4-verified) ----
template<int DIR>
__device__ __forceinline__ void load_A(const float* __restrict__ trans, short8 A[4][2],
                                       int q, int col) {
  const int mrow = 16 * (col >> 2) + (col & 3);
  #pragma unroll
  for (int t = 0; t < 4; ++t) {
    #pragma unroll
    for (int c = 0; c < 2; ++c) {
      short8 a;
      #pragma unroll
      for (int j = 0; j < 8; ++j) {
        int R = mrow + 4 * t, K = 16 * q + 8 * c + j;
        float tv = (DIR == 0) ? trans[R * 64 + K] : trans[K * 64 + R];
        a[j] = bf16_rne(__expf(tv));
      }
      A[t][c] = a;
    }
  }
}

template<int DIR>
__device__ __forceinline__ void epilogue(float* __restrict__ ws, const float W[16],
                                         float C, int g, int lane, int q, int col) {
  float* slab = ws + (size_t)(g * 2 + DIR) * 1024;
  #pragma unroll
  for (int t4 = 0; t4 < 4; ++t4) {
    vf4 o = {W[t4 * 4], W[t4 * 4 + 1], W[t4 * 4 + 2], W[t4 * 4 + 3]};
    *(vf4*)(slab + lane * 16 + t4 * 4) = o;
  }
  if (q == 0) ws[65536 + (g * 2 + DIR) * 16 + col] = C;
}

// One recurrence step: Fs[t][i] = e[4t+i] = exp(feat[tag 16q+4t+i]) as f32.
// Bit-identical consumption mapping to the verified legacy path.
template<int DIR>
__device__ __forceinline__ void crf_step(const vf4 (&Fs)[4], const short8 (&A)[4][2],
                                         float (&W)[16]) {
  float P[16];
  #pragma unroll
  for (int t = 0; t < 4; ++t)
    #pragma unroll
    for (int i = 0; i < 4; ++i)
      P[t * 4 + i] = (DIR == 0) ? W[t * 4 + i] : W[t * 4 + i] * Fs[t][i];

  union { unsigned uu[4]; short8 s8; } B0, B1;
  B0.uu[0] = pk_bf16(P[0], P[1]);   B0.uu[1] = pk_bf16(P[2], P[3]);
  B0.uu[2] = pk_bf16(P[4], P[5]);   B0.uu[3] = pk_bf16(P[6], P[7]);
  B1.uu[0] = pk_bf16(P[8], P[9]);   B1.uu[1] = pk_bf16(P[10], P[11]);
  B1.uu[2] = pk_bf16(P[12], P[13]); B1.uu[3] = pk_bf16(P[14], P[15]);

  vf4 z4 = {0.f, 0.f, 0.f, 0.f};
  vf4 d0 = mfma16(A[0][0], B0.s8, z4);
  vf4 d1 = mfma16(A[1][0], B0.s8, z4);
  vf4 d2 = mfma16(A[2][0], B0.s8, z4);
  vf4 d3 = mfma16(A[3][0], B0.s8, z4);
  d0 = mfma16(A[0][1], B1.s8, d0);
  d1 = mfma16(A[1][1], B1.s8, d1);
  d2 = mfma16(A[2][1], B1.s8, d2);
  d3 = mfma16(A[3][1], B1.s8, d3);

  #pragma unroll
  for (int i = 0; i < 4; ++i) {
    W[i]      = (DIR == 0) ? d0[i] * Fs[0][i] : d0[i];
    W[4 + i]  = (DIR == 0) ? d1[i] * Fs[1][i] : d1[i];
    W[8 + i]  = (DIR == 0) ? d2[i] * Fs[2][i] : d2[i];
    W[12 + i] = (DIR == 0) ? d3[i] * Fs[3][i] : d3[i];
  }
}

// ---------------------------------------------------------------------------
// Producer: wave 1 streams one 8-step chunk (32KB) of this chain's feats into
// an LDS buffer. Lane l=(q*16+col) handles batch g*16+col, floats 16q..16q+15
// per step (one contiguous 64B piece, 4 vf4 loads), stored so the consumer's
// reads are the standard lane-stride-16B ds_read_b128 pattern.
// ---------------------------------------------------------------------------
template<int DIR>
__device__ __forceinline__ void produce_chunk(const float* __restrict__ feats,
                                              float* dst, int g, int lane, int c) {
  const int q = lane >> 4, col = lane & 15;
  const int b = g * 16 + col;
  const int jb = c * 8;
  #pragma unroll
  for (int st = 0; st < 8; ++st) {
    const int j = jb + st;
    const int s = (DIR == 0) ? j : (1023 - j);
    const float* src = feats + (size_t)b * 65536 + (size_t)s * 64 + 16 * q;
    #pragma unroll
    for (int k = 0; k < 4; ++k) {
      vf4 v = *(const vf4*)(src + 4 * k);
      *(vf4*)(dst + st * 1024 + k * 256 + lane * 4) = v;
    }
  }
}

// Consumer: wave 0 runs 8 recurrence steps from an LDS buffer.
template<int DIR>
__device__ __forceinline__ void consume_chunk(const float* buf, const short8 (&A)[4][2],
                                              float (&W)[16], float& C, float& zpend,
                                              int lane, int col) {
  #pragma unroll
  for (int st = 0; st < 8; ++st) {
    vf4 Es[4];
    #pragma unroll
    for (int k = 0; k < 4; ++k) {
      vf4 r = *(const vf4*)(buf + st * 1024 + k * 256 + lane * 4);
      #pragma unroll
      for (int i = 0; i < 4; ++i) Es[k][i] = __expf(r[i]);
    }
    crf_step<DIR>(Es, A, W);
    if ((st & 3) == 3) {
      // pipelined renorm (R5-verified): apply z measured 4 steps ago
      float rz = __builtin_amdgcn_rcpf(zpend);
      C += __logf(zpend);
      #pragma unroll
      for (int i = 0; i < 16; ++i) W[i] *= rz;
      zpend = __shfl(W[0], col);                // true-tag-0 weight (> 0)
    }
  }
}

// ---------------------------------------------------------------------------
// Fast path: producer/consumer wave pair, double-buffered LDS (2 x 32KB).
// The producer's vmcnt(0) drain before each barrier overlaps the consumer's
// ~2400cy chunk compute -> HBM latency off the serial path. No inline asm.
// ---------------------------------------------------------------------------
template<int DIR>
__device__ __forceinline__ void chain_fast_pc(const float* __restrict__ feats,
                                              const float* __restrict__ trans,
                                              float* __restrict__ ws, int g,
                                              float* lds) {
  const int tid = threadIdx.x;
  const int wid = tid >> 6;
  const int lane = tid & 63;
  const int q = lane >> 4, col = lane & 15;

  short8 A[4][2];
  float W[16];
  float C = 0.f, zpend = 1.f;

  if (wid == 0) {
    load_A<DIR>(trans, A, q, col);
    if (DIR == 0) {
      #pragma unroll
      for (int i = 0; i < 16; ++i) W[i] = 0.f;
      if (q == 3) W[14] = 1.f;                  // true tag 62 = START
    } else {
      #pragma unroll
      for (int i = 0; i < 16; ++i) W[i] = __expf(trans[STOP_TAG * 64 + 16 * q + i]);
    }
  }

  if (wid == 1) produce_chunk<DIR>(feats, lds, g, lane, 0);
  __syncthreads();

  for (int c = 0; c < 64; ++c) {
    if (wid == 1) {
      if (c + 1 < 64)
        produce_chunk<DIR>(feats, lds + ((c + 1) & 1) * 8192, g, lane, c + 1);
    } else {
      consume_chunk<DIR>(lds + (c & 1) * 8192, A, W, C, zpend, lane, col);
    }
    __syncthreads();
  }

  if (wid == 0) epilogue<DIR>(ws, W, C, g, lane, q, col);
}

// Masked path (general mask) — plain loads, per-step mask select (R4-verified).
// Run by wave 0 only; no barriers.
template<int DIR>
__device__ __forceinline__ void chain_masked(const float* __restrict__ feats,
                                             const float* __restrict__ trans,
                                             const int* __restrict__ mask,
                                             float* __restrict__ ws, int g) {
  const int lane = threadIdx.x & 63;
  const int q = lane >> 4, col = lane & 15;
  const int b = g * 16 + col;

  short8 A[4][2];
  load_A<DIR>(trans, A, q, col);

  float W[16];
  float C = 0.f;
  if (DIR == 0) {
    #pragma unroll
    for (int i = 0; i < 16; ++i) W[i] = 0.f;
    if (q == 3) W[14] = 1.f;
  } else {
    #pragma unroll
    for (int i = 0; i < 16; ++i) W[i] = __expf(trans[STOP_TAG * 64 + 16 * q + i]);
  }

  const char* gb = (const char*)feats + (size_t)b * 262144 + (size_t)q * 64;
  vf4 cur[4];
  {
    size_t s0 = (DIR == 0) ? 0 : 1023;
    #pragma unroll
    for (int v = 0; v < 4; ++v)
      cur[v] = *(const vf4*)(gb + s0 * 256 + (size_t)v * 16);
  }

  for (int grp = 0; grp < 128; ++grp) {
    #pragma unroll
    for (int u = 0; u < 4; ++u) {
      const int j = grp * 4 + u;
      float e[16];
      #pragma unroll
      for (int v = 0; v < 4; ++v)
        #pragma unroll
        for (int i = 0; i < 4; ++i) e[v * 4 + i] = __expf(cur[v][i]);

      float P[16];
      #pragma unroll
      for (int i = 0; i < 16; ++i) P[i] = (DIR == 0) ? W[i] : W[i] * e[i];

      union { unsigned uu[4]; short8 s8; } B0, B1;
      B0.uu[0] = pk_bf16(P[0], P[1]);   B0.uu[1] = pk_bf16(P[2], P[3]);
      B0.uu[2] = pk_bf16(P[4], P[5]);   B0.uu[3] = pk_bf16(P[6], P[7]);
      B1.uu[0] = pk_bf16(P[8], P[9]);   B1.uu[1] = pk_bf16(P[10], P[11]);
      B1.uu[2] = pk_bf16(P[12], P[13]); B1.uu[3] = pk_bf16(P[14], P[15]);

      vf4 z4 = {0.f, 0.f, 0.f, 0.f};
      vf4 d0 = mfma16(A[0][0], B0.s8, z4);
      vf4 d1 = mfma16(A[1][0], B0.s8, z4);
      vf4 d2 = mfma16(A[2][0], B0.s8, z4);
      vf4 d3 = mfma16(A[3][0], B0.s8, z4);
      d0 = mfma16(A[0][1], B1.s8, d0);
      d1 = mfma16(A[1][1], B1.s8, d1);
      d2 = mfma16(A[2][1], B1.s8, d2);
      d3 = mfma16(A[3][1], B1.s8, d3);

      int sj = (DIR == 0) ? j : 1023 - j;
      int m = mask[b * 1024 + sj];
      int sn = (DIR == 0) ? (j + 1) : 1023 - (j + 1);
      #pragma unroll
      for (int v = 0; v < 4; ++v)
        cur[v] = *(const vf4*)(gb + (size_t)sn * 256 + (size_t)v * 16);

      #pragma unroll
      for (int i = 0; i < 4; ++i) {
        float n0 = (DIR == 0) ? d0[i] * e[i]      : d0[i];
        float n1 = (DIR == 0) ? d1[i] * e[4 + i]  : d1[i];
        float n2 = (DIR == 0) ? d2[i] * e[8 + i]  : d2[i];
        float n3 = (DIR == 0) ? d3[i] * e[12 + i] : d3[i];
        W[i]      = m ? n0 : W[i];
        W[4 + i]  = m ? n1 : W[4 + i];
        W[8 + i]  = m ? n2 : W[8 + i];
        W[12 + i] = m ? n3 : W[12 + i];
      }
    }
    float z = __shfl(W[0], col);
    float rz = __builtin_amdgcn_rcpf(z);
    C += __logf(z);
    #pragma unroll
    for (int i = 0; i < 16; ++i) W[i] *= rz;
  }
  epilogue<DIR>(ws, W, C, g, lane, q, col);
}

// Blocks 0..63: chains (g=blk>>1, dir=blk&1), 2 waves (consumer+producer).
// Blocks 64..575: gold score for batch blk-64 (wave 0 only).
__global__ __launch_bounds__(128, 1)
void crf_main(const float* __restrict__ feats, const float* __restrict__ trans,
              const int* __restrict__ tags, const int* __restrict__ mask,
              float* __restrict__ ws) {
  __shared__ float lds[16384];                  // 2 x 32KB chunk buffers
  const int blk = blockIdx.x;
  const int wid = threadIdx.x >> 6;
  if (blk < NCHAIN) {
    const int g = blk >> 1, dir = blk & 1;
    const int lane = threadIdx.x & 63;
    const int q = lane >> 4;
    const int col = lane & 15;
    const int b = g * 16 + col;
    const int sB = dir ? 512 : 0;
    int anyz = 0;
    for (int it = 0; it < 32; ++it) {
      int4 v = *(const int4*)(mask + b * 1024 + sB + (it * 4 + q) * 4);
      anyz |= (v.x == 0) | (v.y == 0) | (v.z == 0) | (v.w == 0);
    }
    // identical per wave (same lane-indexed data) -> block-uniform branch
    bool allones = (__ballot(anyz != 0) == 0ull);
    if (allones) {
      if (dir == 0) chain_fast_pc<0>(feats, trans, ws, g, lds);
      else          chain_fast_pc<1>(feats, trans, ws, g, lds);
    } else {
      if (wid == 0) {
        if (dir == 0) chain_masked<0>(feats, trans, mask, ws, g);
        else          chain_masked<1>(feats, trans, mask, ws, g);
      }
    }
    (void)tags;
  } else {
    if (wid != 0) return;
    const int b = blk - NCHAIN;
    const int* tb = tags + b * SLEN;
    const int* mb = mask + b * SLEN;
    const float* fbg = feats + (size_t)b * 65536;
    float acc = 0.f, cnt = 0.f;
    const int t = threadIdx.x & 63;
    for (int k = 0; k < 16; ++k) {
      int s = t + k * 64;
      int cur = tb[s];
      int prev = (s == 0) ? START_TAG : tb[s - 1];
      float m = (float)mb[s];
      acc += m * (fbg[s * 64 + cur] + trans[cur * 64 + prev]);
      cnt += m;
    }
    #pragma unroll
    for (int o = 1; o < 64; o <<= 1) {
      acc += __shfl_xor(acc, o);
      cnt += __shfl_xor(cnt, o);
    }
    if (t == 0) {
      int last_idx = (int)(cnt + 0.5f);
      int last_tag = (last_idx == 0) ? START_TAG : tb[last_idx - 1];
      ws[66560 + b] = acc + trans[STOP_TAG * 64 + last_tag];
    }
  }
}

__global__ __launch_bounds__(512)
void crf_reduce(const float* __restrict__ ws, float* __restrict__ out) {
  __shared__ float s[512];
  const int t = threadIdx.x;
  const int g = t >> 4, col = t & 15;
  const float* Wf = ws + (size_t)(2 * g) * 1024;
  const float* Wb = ws + (size_t)(2 * g + 1) * 1024;
  float P = 0.f;
  #pragma unroll
  for (int q = 0; q < 4; ++q)
    #pragma unroll
    for (int i = 0; i < 16; ++i)
      P += Wf[(q * 16 + col) * 16 + i] * Wb[(q * 16 + col) * 16 + i];
  float sc = ws[65536 + (2 * g) * 16 + col] + ws[65536 + (2 * g + 1) * 16 + col] + __logf(P);
  s[t] = sc - ws[66560 + t];
  __syncthreads();
  for (int off = 256; off > 0; off >>= 1) {
    if (t < off) s[t] += s[t + off];
    __syncthreads();
  }
  if (t == 0) out[0] = s[0] * (1.f / 512.f);
}

extern "C" void kernel_launch(void* const* d_in, const int* in_sizes, int n_in,
                              void* d_out, int out_size, void* d_ws, size_t ws_size,
                              hipStream_t stream) {
  const float* feats = (const float*)d_in[0];
  const float* trans = (const float*)d_in[1];
  const int* tags = (const int*)d_in[2];
  const int* mask = (const int*)d_in[3];
  float* ws = (float*)d_ws;
  float* out = (float*)d_out;

  crf_main<<<NCHAIN + BATCH, 128, 0, stream>>>(feats, trans, tags, mask, ws);
  crf_reduce<<<1, 512, 0, stream>>>(ws, out);
}